// Round 10
// baseline (119.128 us; speedup 1.0000x reference)
//
#include <hip/hip_runtime.h>
#include <math.h>

// (N, Cin, Cout, S, H, W) = (4, 256, 256, 512, 64, 64)
#define NB 4
#define CC 256
#define SS 512
#define NL 6
#define SLOT_HW 65536   // 128 KB per weight slot, MFMA-A-fragment-packed
// ws layout (halfwords): slots 0..6 (conv + 6x mod_w[l]) = [0, 458752)
//   g table float[6144] at halfword offset 458752 (byte 917504)
#define G_OFF_HW   (7*SLOT_HW)

typedef __attribute__((ext_vector_type(8))) short s16x8;
typedef __attribute__((ext_vector_type(4))) float f32x4;
typedef __attribute__((ext_vector_type(2))) float f32x2;

__device__ __forceinline__ unsigned short f2bf(float f) {
    unsigned u = __builtin_bit_cast(unsigned, f);
    u += 0x7FFFu + ((u >> 16) & 1u);
    return (unsigned short)(u >> 16);
}
// packed RNE f32->bf16 pair
__device__ __forceinline__ unsigned cvt_pk_bf16(float lo, float hi) {
    unsigned r;
    asm("v_cvt_pk_bf16_f32 %0, %1, %2" : "=v"(r) : "v"(lo), "v"(hi));
    return r;
}
// gelu_exact(x) ~= x*sigmoid(1.5957691216*(x+0.044715x^3)), |err|<3e-3
__device__ __forceinline__ float gelu_fast(float x) {
    float u = x * (1.0f + 0.044715f * x * x);
    float e = __expf(-1.5957691216f * u);
    return x * __builtin_amdgcn_rcpf(1.0f + e);
}
// un-rematerializable prefetch load: result registers MUST be kept
__device__ __forceinline__ s16x8 aload(const unsigned short* p) {
    s16x8 r;
    asm volatile("global_load_dwordx4 %0, %1, off" : "=v"(r) : "v"(p));
    return r;
}

// ---------------------------------------------------------------------------
// Prep (unchanged): g-factorization -> 7 batch-independent A-slots + g table.
__global__ __launch_bounds__(256) void prep_kernel(
    const float* __restrict__ y, const float* __restrict__ aw,
    const float* __restrict__ ab, const float* __restrict__ mw,
    const float* __restrict__ cw, unsigned short* __restrict__ wsBF)
{
    int w = threadIdx.x >> 6, lane = threadIdx.x & 63;
    float* gtab = (float*)(wsBF + G_OFF_HW);

    if (blockIdx.x < 448) {            // slot packing: row = slot*256 + m
        int row = blockIdx.x*4 + w;    // 0..1791
        int sl  = row >> 8, m = row & 255;
        const float* src = (sl == 0) ? (cw + (size_t)m*CC)
                                     : (mw + ((size_t)(sl-1)*CC + m)*CC);
        unsigned short* dst = wsBF + (size_t)sl*SLOT_HW;
#pragma unroll
        for (int u = 0; u < 4; ++u) {
            int k = lane + 64*u;
            int f = (m >> 4)*8 + (k >> 5);
            int hw = f*512 + ((k >> 3) & 3)*128 + (m & 15)*8 + (k & 7);
            dst[hw] = f2bf(src[k]);
        }
        return;
    }

    int r  = (blockIdx.x - 448)*4 + w; // 0..1535 = (layer, out-channel)
    int pl = r >> 8, po = r & 255;

    const float* awr = aw + (size_t)(pl*CC + po)*SS;
    float s[4] = {0.f, 0.f, 0.f, 0.f};
#pragma unroll
    for (int j = 0; j < 8; ++j) {
        int idx = lane + 64*j;
        float a = awr[idx];
#pragma unroll
        for (int b = 0; b < 4; ++b) s[b] += a * y[(size_t)b*SS + idx];
    }
    const float* mwr = mw + ((size_t)pl*CC + po)*CC;
    float qs = 0.f;
#pragma unroll
    for (int u = 0; u < 4; ++u) { float v = mwr[lane + 64*u]; qs += v*v; }
#pragma unroll
    for (int off = 32; off; off >>= 1) {
#pragma unroll
        for (int b = 0; b < 4; ++b) s[b] += __shfl_xor(s[b], off);
        qs += __shfl_xor(qs, off);
    }
    float abv = ab[pl*CC + po];
    if (lane < 4) {
        float t = s[lane] + abv + 1.0f;
        gtab[pl*1024 + lane*256 + po] = t * (1.0f / sqrtf(t*t*qs + 1e-8f));
    }
}

// ---------------------------------------------------------------------------
// Fused: 512 blocks x 512 thr, 2 blocks/CU. TRUE A-prefetch (asm-volatile
// loads + counted vmcnt). NEW: anti-phase stagger — co-resident block pairs
// are (i, i+256); blocks with bit 8 set sleep ~7k cycles at entry so each
// CU's two blocks run half-a-layer out of phase (barrier stalls of one are
// covered by MFMA/VALU of the other; identical-code blocks otherwise
// phase-lock and stall simultaneously).
#define BFRAGL(buf, kq, nt, kcl) \
    (lds + (buf)*16384 + ((((kq)*2 + (nt))*2 + (kcl)))*1024)

// issue both t-halves of A slot p (literal p)
#define ISSUE(p) { \
    aS[p][0] = aload(slot + (size_t)(((2*w+0)*8 + (p))*512) + lane*8); \
    aS[p][1] = aload(slot + (size_t)(((2*w+1)*8 + (p))*512) + lane*8); }
// wait until <=N vmem outstanding; ties slot st's regs so dependent MFMAs
// cannot be scheduled above the wait
#define WAITA(N, st) asm volatile("s_waitcnt vmcnt(" #N ")" \
    : "+v"(aS[st][0]), "+v"(aS[st][1]))
#define STEPX(st) { \
    s16x8 b0 = *(const s16x8*)(BFRAGL(buf,(st)>>1,0,(st)&1) + lane*16); \
    s16x8 b1 = *(const s16x8*)(BFRAGL(buf,(st)>>1,1,(st)&1) + lane*16); \
    acc[0][0] = __builtin_amdgcn_mfma_f32_16x16x32_bf16(aS[st][0], b0, acc[0][0],0,0,0); \
    acc[1][0] = __builtin_amdgcn_mfma_f32_16x16x32_bf16(aS[st][1], b0, acc[1][0],0,0,0); \
    acc[0][1] = __builtin_amdgcn_mfma_f32_16x16x32_bf16(aS[st][0], b1, acc[0][1],0,0,0); \
    acc[1][1] = __builtin_amdgcn_mfma_f32_16x16x32_bf16(aS[st][1], b1, acc[1][1],0,0,0); \
}
#define MFMA_PHASE() \
    ISSUE(5); WAITA(10,0); STEPX(0); \
    ISSUE(6); WAITA(10,1); STEPX(1); \
    ISSUE(7); WAITA(10,2); STEPX(2); \
    WAITA(8,3);  STEPX(3); \
    WAITA(6,4);  STEPX(4); \
    WAITA(4,5);  STEPX(5); \
    WAITA(2,6);  STEPX(6); \
    WAITA(0,7);  STEPX(7);
#define RAW_BARRIER() { \
    asm volatile("s_waitcnt lgkmcnt(0)" ::: "memory"); \
    __builtin_amdgcn_s_barrier(); }

__global__ __launch_bounds__(512, 4) void fused_kernel(
    const float* __restrict__ x, const float* __restrict__ cb,
    const unsigned short* __restrict__ wsBF, float* __restrict__ out)
{
    // LDS 75776 B: layer-B dbuf [0,32K) | conv region @32768: xS f32[256][36]
    // (36864 B), overlaid by S2 f32[256][33] in the epilogue | g LDS @69632
    // (6 KB, this block's batch slice of gtab). 2 blocks/CU (151.5 KB).
    __shared__ __align__(16) unsigned char lds[75776];
    float* xS = (float*)(lds + 32768);
    float* S2 = (float*)(lds + 32768);
    float* gS = (float*)(lds + 69632);
    const float* gtab = (const float*)(wsBF + G_OFF_HW);

    // anti-phase stagger: pair (i, i+256) shares a CU; late half sleeps
    // ~7040 cycles (~half a layer period) to break barrier phase-lock
    if (blockIdx.x & 256) __builtin_amdgcn_s_sleep(110);

    const int tid  = threadIdx.x;
    const int lane = tid & 63;
    const int w    = tid >> 6;     // wave 0..7: owns m-rows [32w, 32w+32)
    const int l15  = lane & 15;
    const int q    = lane >> 4;    // 0..3

    // XCD swizzle: blockIdx%8 -> (batch, half) per XCD
    const int bswz  = blockIdx.x & 7;
    const int b     = bswz >> 1;               // 0..3
    const int half  = bswz & 1;                // 0..1
    const int strip = blockIdx.x >> 3;         // 0..63
    const int n0    = strip * 64 + half * 32;  // 32-px window

    float y1[2][2][4], y2[2][2][4];
    f32x4 acc[2][2];
    s16x8 aS[8][2];

    // ---------------- conv GEMM:  acc = cw @ x[b] ----------------
#pragma unroll
    for (int t = 0; t < 2; ++t)
#pragma unroll
        for (int s = 0; s < 2; ++s) acc[t][s] = 0;

    // g slice -> LDS (C++ VMEM, fully waited by compiler before our asm)
    if (tid < 384) {
        int gl = tid >> 6, gm = (tid & 63) * 4;
        float4 gvv = *(const float4*)&gtab[gl*1024 + b*256 + gm];
        *(float4*)&gS[gl*256 + gm] = gvv;
    }
    // x window -> LDS, coalesced
#pragma unroll
    for (int p = 0; p < 4; ++p) {
        int row = (tid >> 3) + 64*p, c4 = (tid & 7) * 4;
        float4 v = *(const float4*)&x[((size_t)(b*CC + row))*4096 + n0 + c4];
        *(float4*)&xS[row*36 + c4] = v;
    }
    // fence: keep compiler's x/g loads+waits above our asm issues
    asm volatile("" ::: "memory");
    {
        const unsigned short* slot = wsBF;
#pragma unroll
        for (int p = 0; p < 5; ++p) ISSUE(p);
        RAW_BARRIER();                 // xS staged (lgkm only; A stays in flight)
        {   // transpose-read (conflict-free) -> bf16 -> ALL conv-B frags (buf0)
            int n = tid & 31, k0 = (tid >> 5) * 16;
            int nt = n >> 4, n15 = n & 15;
#pragma unroll
            for (int j = 0; j < 4; ++j) {
                int k = k0 + 4*j;
                float v0 = xS[(k+0)*36 + n], v1 = xS[(k+1)*36 + n];
                float v2 = xS[(k+2)*36 + n], v3 = xS[(k+3)*36 + n];
                uint2 hv; hv.x = cvt_pk_bf16(v0, v1); hv.y = cvt_pk_bf16(v2, v3);
                int kq = k >> 6, kcl = (k >> 5) & 1, qq = (k >> 3) & 3, jb = k & 7;
                *(uint2*)(BFRAGL(0,kq,nt,kcl) + (16*qq + n15)*16 + jb*2) = hv;
            }
        }
        RAW_BARRIER();                 // frags ready
        const int buf = 0;
        __builtin_amdgcn_s_setprio(1);
        MFMA_PHASE();
        __builtin_amdgcn_s_setprio(0);
    }

    // conv epilogue, single pass via S2[256][33] (vmcnt=0 here; __syncthreads ok)
#pragma unroll
    for (int t = 0; t < 2; ++t)
#pragma unroll
    for (int s = 0; s < 2; ++s)
#pragma unroll
    for (int r = 0; r < 4; ++r) {
        int m  = 32*w + 16*t + 4*q + r;
        int nl = 16*s + l15;
        S2[m*33 + nl] = acc[t][s][r] + cb[m];
    }
    __syncthreads();
#pragma unroll
    for (int t = 0; t < 2; ++t)
#pragma unroll
    for (int s = 0; s < 2; ++s)
#pragma unroll
    for (int r = 0; r < 4; ++r) {
        int c  = 32*w + 16*t + 4*q + r;
        int nl = 16*s + l15;
        float a  = S2[(c >> 1)*33 + nl];
        float bb = S2[(128 + (c >> 1))*33 + nl];
        y1[t][s][r] = a + bb;          // x1 + x2
        y2[t][s][r] = bb;              // x2
    }

    // ---------------- 6 layers: ONE raw barrier per layer (B dbuf) ----------
    for (int l = 0; l < NL; ++l) {
        const int buf = l & 1;
        const unsigned short* slot = wsBF + (size_t)(1 + l)*SLOT_HW;
#pragma unroll
        for (int t = 0; t < 2; ++t)
#pragma unroll
            for (int s = 0; s < 2; ++s) acc[t][s] = 0;

        asm volatile("" ::: "memory");
#pragma unroll
        for (int p = 0; p < 5; ++p) ISSUE(p);   // A prefetch, stays in flight

        // stage B (bf16) from y1 regs: wave w's rows = k-slice [32w,32w+32)
        {
            int kq = w >> 1, kcl = w & 1, jb = 4*(q & 1);
#pragma unroll
            for (int t = 0; t < 2; ++t) {
                int qq = 2*t + (q >> 1);
#pragma unroll
                for (int s = 0; s < 2; ++s) {
                    uint2 hv;
                    hv.x = cvt_pk_bf16(y1[t][s][0], y1[t][s][1]);
                    hv.y = cvt_pk_bf16(y1[t][s][2], y1[t][s][3]);
                    *(uint2*)(BFRAGL(buf,kq,s,kcl) + (16*qq + l15)*16 + jb*2) = hv;
                }
            }
        }
        RAW_BARRIER();                 // B ready; A prefetch still in flight
        __builtin_amdgcn_s_setprio(1);
        MFMA_PHASE();
        __builtin_amdgcn_s_setprio(0);

        // g from LDS (lgkm path only; no vmcnt interference)
        float4 gv[2];
#pragma unroll
        for (int t = 0; t < 2; ++t)
            gv[t] = *(const float4*)&gS[l*256 + 32*w + 16*t + 4*q];

        if (l < NL - 1) {
#pragma unroll
            for (int t = 0; t < 2; ++t)
#pragma unroll
            for (int s = 0; s < 2; ++s)
#pragma unroll
            for (int r = 0; r < 4; ++r) {
                y2[t][s][r] += gelu_fast(acc[t][s][r] * gv[t][r]);
                y1[t][s][r] += y2[t][s][r];
            }
        } else {
            // LAST layer: fuse epilogue into the 2x2-upsample store
#pragma unroll
            for (int t = 0; t < 2; ++t)
#pragma unroll
            for (int s = 0; s < 2; ++s)
#pragma unroll
            for (int r = 0; r < 4; ++r) {
                float yf = y2[t][s][r] + gelu_fast(acc[t][s][r] * gv[t][r]);
                float v  = 0.5f*(y1[t][s][r] + yf);
                int ch  = 32*w + 16*t + 4*q + r;
                int wpx = half*32 + 16*s + l15;       // 0..63 source col
                f32x2 vv = {v, v};
                size_t base = (((size_t)(b*CC + ch)*128 + 2*strip))*128 + 2*wpx;
                __builtin_nontemporal_store(vv, (f32x2*)&out[base]);
                __builtin_nontemporal_store(vv, (f32x2*)&out[base + 128]);
            }
        }
    }
}

extern "C" void kernel_launch(void* const* d_in, const int* in_sizes, int n_in,
                              void* d_out, int out_size, void* d_ws, size_t ws_size,
                              hipStream_t stream) {
    const float* x  = (const float*)d_in[0];
    const float* y  = (const float*)d_in[1];
    const float* cw = (const float*)d_in[2];
    const float* cb = (const float*)d_in[3];
    const float* aw = (const float*)d_in[4];
    const float* ab = (const float*)d_in[5];
    const float* mw = (const float*)d_in[6];
    float* out = (float*)d_out;

    unsigned short* wsBF = (unsigned short*)d_ws;   // 7 slots + g table < 1 MB

    prep_kernel<<<832, 256, 0, stream>>>(y, aw, ab, mw, cw, wsBF);
    fused_kernel<<<512, 512, 0, stream>>>(x, cb, wsBF, out);
}